// Round 1
// baseline (853.166 us; speedup 1.0000x reference)
//
#include <hip/hip_runtime.h>

#define S_STEPS 64
#define BM 64
#define BN 64
#define BK 32
#define LDP 68   // padded LDS row stride (floats): keeps float4 alignment, breaks pow-2 banks

// ---------------- encoder: r[b,f] = mean_t( (x[b,t,f]-x[b-1,t,f]) >= 0.2 ) ----------------
__global__ void snn_encoder(const float* __restrict__ x, float* __restrict__ r,
                            int B, int T, int F) {
    int idx = blockIdx.x * blockDim.x + threadIdx.x;   // b*F + f
    if (idx >= B * F) return;
    int b = idx / F;
    int f = idx - b * F;
    if (b == 0) { r[idx] = 0.0f; return; }             // x[0]-x[0] = 0 < 0.2
    const float* xb = x + (size_t)b * T * F + f;
    const float* xp = xb - (size_t)T * F;
    int cnt = 0;
    for (int t = 0; t < T; ++t) {
        float d = __fsub_rn(xb[(size_t)t * F], xp[(size_t)t * F]);
        cnt += (d >= 0.2f) ? 1 : 0;
    }
    // mean over T=128: integer count * 2^-7, exact — bitwise equal to np sum/128
    r[idx] = (float)cnt * (1.0f / 128.0f);
}

// ---------------- tiled fp32 GEMM: C[M,N] = A[M,K] * Bw[N,K]^T + bias[N] ----------------
__global__ __launch_bounds__(256)
void snn_gemm_nt(const float* __restrict__ A, const float* __restrict__ Bw,
                 const float* __restrict__ bias, float* __restrict__ C,
                 int M, int N, int K) {
    __shared__ __align__(16) float As[BK][LDP];
    __shared__ __align__(16) float Bs[BK][LDP];
    const int t  = threadIdx.x;
    const int m0 = blockIdx.y * BM;
    const int n0 = blockIdx.x * BN;
    const int tx = t & 15;          // n direction (16)
    const int ty = t >> 4;          // m direction (16)
    const int lrow = t >> 3;        // staging row 0..31
    const int lcol = (t & 7) << 2;  // staging k-offset 0,4,...,28

    float acc[4][4] = {};

    for (int k0 = 0; k0 < K; k0 += BK) {
        float4 a0 = *(const float4*)(A  + (size_t)(m0 + lrow)      * K + k0 + lcol);
        float4 a1 = *(const float4*)(A  + (size_t)(m0 + lrow + 32) * K + k0 + lcol);
        float4 b0 = *(const float4*)(Bw + (size_t)(n0 + lrow)      * K + k0 + lcol);
        float4 b1 = *(const float4*)(Bw + (size_t)(n0 + lrow + 32) * K + k0 + lcol);
        __syncthreads();
        As[lcol + 0][lrow] = a0.x; As[lcol + 1][lrow] = a0.y;
        As[lcol + 2][lrow] = a0.z; As[lcol + 3][lrow] = a0.w;
        As[lcol + 0][lrow + 32] = a1.x; As[lcol + 1][lrow + 32] = a1.y;
        As[lcol + 2][lrow + 32] = a1.z; As[lcol + 3][lrow + 32] = a1.w;
        Bs[lcol + 0][lrow] = b0.x; Bs[lcol + 1][lrow] = b0.y;
        Bs[lcol + 2][lrow] = b0.z; Bs[lcol + 3][lrow] = b0.w;
        Bs[lcol + 0][lrow + 32] = b1.x; Bs[lcol + 1][lrow + 32] = b1.y;
        Bs[lcol + 2][lrow + 32] = b1.z; Bs[lcol + 3][lrow + 32] = b1.w;
        __syncthreads();

        // per-tile partial accumulator: two-level sum keeps rounding ~pairwise-class
        float accT[4][4] = {};
        #pragma unroll
        for (int kk = 0; kk < BK; ++kk) {
            float4 av = *(const float4*)(&As[kk][ty << 2]);
            float4 bv = *(const float4*)(&Bs[kk][tx << 2]);
            float a[4] = {av.x, av.y, av.z, av.w};
            float b[4] = {bv.x, bv.y, bv.z, bv.w};
            #pragma unroll
            for (int i = 0; i < 4; ++i)
                #pragma unroll
                for (int j = 0; j < 4; ++j)
                    accT[i][j] = fmaf(a[i], b[j], accT[i][j]);
        }
        #pragma unroll
        for (int i = 0; i < 4; ++i)
            #pragma unroll
            for (int j = 0; j < 4; ++j)
                acc[i][j] += accT[i][j];
    }

    #pragma unroll
    for (int i = 0; i < 4; ++i) {
        int m = m0 + (ty << 2) + i;
        float4 out;
        out.x = acc[i][0] + bias[n0 + (tx << 2) + 0];
        out.y = acc[i][1] + bias[n0 + (tx << 2) + 1];
        out.z = acc[i][2] + bias[n0 + (tx << 2) + 2];
        out.w = acc[i][3] + bias[n0 + (tx << 2) + 3];
        *(float4*)(C + (size_t)m * N + n0 + (tx << 2)) = out;
    }
}

// ---------------- LIF scan: 64 steps, fp32 ops bit-matching the reference formula ----------------
__global__ void snn_lif(const float* __restrict__ cur, float* __restrict__ spk,
                        int BH, int bcast) {
    int idx = blockIdx.x * blockDim.x + threadIdx.x;
    if (idx >= BH) return;
    float mem = 0.0f;
    float cconst = bcast ? cur[idx] : 0.0f;
    for (int s = 0; s < S_STEPS; ++s) {
        float c = bcast ? cconst : cur[(size_t)s * BH + idx];
        float reset = (mem > 1.0f) ? 1.0f : 0.0f;        // heaviside(mem - 1): sub is sign-exact
        float m1 = __fmul_rn(0.9f, mem);                  // BETA*mem   (no fma contraction)
        m1 = __fadd_rn(m1, c);                            // + cur
        m1 = __fsub_rn(m1, reset);                        // - reset*1.0
        mem = m1;
        spk[(size_t)s * BH + idx] = (mem > 1.0f) ? 1.0f : 0.0f;
    }
}

extern "C" void kernel_launch(void* const* d_in, const int* in_sizes, int n_in,
                              void* d_out, int out_size, void* d_ws, size_t ws_size,
                              hipStream_t stream) {
    const float* x  = (const float*)d_in[0];
    const float* W0 = (const float*)d_in[1];
    const float* b0 = (const float*)d_in[2];
    const float* W1 = (const float*)d_in[3];
    const float* b1 = (const float*)d_in[4];
    const float* W2 = (const float*)d_in[5];
    const float* b2 = (const float*)d_in[6];

    const int B = 256, T = 128, F = 512, H1 = 1024, H2 = 1024, H3 = 512, S = S_STEPS;

    float* ws   = (float*)d_ws;
    float* r    = ws;                     // B*F        = 131072 floats
    float* cur0 = ws + 131072;            // B*H1       = 262144 floats
    float* bufA = ws + 524288;            // S*B*H1     = 16777216 floats (spk0, later spk1)
    float* bufB = bufA + 16777216;        // S*B*H1     (cur1, later cur2)
    // total: ~134 MB

    // 1. delta encoder -> rates
    snn_encoder<<<dim3((B * F + 255) / 256), dim3(256), 0, stream>>>(x, r, B, T, F);
    // 2. cur0[b,h] = r @ W0^T + b0   (input identical across all S steps)
    snn_gemm_nt<<<dim3(H1 / BN, B / BM), dim3(256), 0, stream>>>(r, W0, b0, cur0, B, H1, F);
    // 3. LIF layer 0 (broadcast current) -> spk0 [S,B,H1]
    snn_lif<<<dim3(B * H1 / 256), dim3(256), 0, stream>>>(cur0, bufA, B * H1, 1);
    // 4. cur1 = spk0 @ W1^T + b1   [16384 x 1024, K=1024]
    snn_gemm_nt<<<dim3(H2 / BN, (S * B) / BM), dim3(256), 0, stream>>>(bufA, W1, b1, bufB, S * B, H2, H1);
    // 5. LIF layer 1 -> spk1 (reuse bufA)
    snn_lif<<<dim3(B * H2 / 256), dim3(256), 0, stream>>>(bufB, bufA, B * H2, 0);
    // 6. cur2 = spk1 @ W2^T + b2   [16384 x 512, K=1024] (reuse bufB)
    snn_gemm_nt<<<dim3(H3 / BN, (S * B) / BM), dim3(256), 0, stream>>>(bufA, W2, b2, bufB, S * B, H3, H2);
    // 7. LIF layer 2 -> d_out
    snn_lif<<<dim3(B * H3 / 256), dim3(256), 0, stream>>>(bufB, (float*)d_out, B * H3, 0);
}

// Round 2
// 483.747 us; speedup vs baseline: 1.7637x; 1.7637x over previous
//
#include <hip/hip_runtime.h>
#include <hip/hip_bf16.h>

#define S_STEPS 64

typedef __bf16 bf16x8 __attribute__((ext_vector_type(8)));
typedef float  f32x4  __attribute__((ext_vector_type(4)));

// ---- async 16B global->LDS (wave-uniform base + lane*16 contiguous dest) ----
__device__ __forceinline__ void async16(const void* g, void* l) {
    __builtin_amdgcn_global_load_lds((const __attribute__((address_space(1))) void*)g,
                                     (__attribute__((address_space(3))) void*)l,
                                     16, 0, 0);
}

// ---------------- encoder: r[b,f] = mean_t( (x[b,t,f]-x[b-1,t,f]) >= 0.2 ) ----------------
// count <= 128 is an integer -> k/128 is EXACT in bf16 (8 significant bits).
__global__ void snn_encoder(const float* __restrict__ x, __hip_bfloat16* __restrict__ r,
                            int B, int T, int F) {
    int idx = blockIdx.x * blockDim.x + threadIdx.x;   // b*F + f
    if (idx >= B * F) return;
    int b = idx / F;
    int f = idx - b * F;
    if (b == 0) { r[idx] = __float2bfloat16(0.0f); return; }
    const float* xb = x + (size_t)b * T * F + f;
    const float* xp = xb - (size_t)T * F;
    int cnt = 0;
    for (int t = 0; t < T; ++t) {
        float d = __fsub_rn(xb[(size_t)t * F], xp[(size_t)t * F]);
        cnt += (d >= 0.2f) ? 1 : 0;
    }
    r[idx] = __float2bfloat16((float)cnt * (1.0f / 128.0f));   // exact
}

// ---------------- 3-way bf16 split of fp32 weights: W == hi + mid + lo (to ~2^-25) ----------------
__global__ void split_w(const float* __restrict__ W,
                        __hip_bfloat16* __restrict__ hi,
                        __hip_bfloat16* __restrict__ mid,
                        __hip_bfloat16* __restrict__ lo, int n) {
    int i = blockIdx.x * blockDim.x + threadIdx.x;
    if (i >= n) return;
    float w = W[i];
    __hip_bfloat16 h = __float2bfloat16(w);
    float r1 = __fsub_rn(w, __bfloat162float(h));      // exact
    __hip_bfloat16 m = __float2bfloat16(r1);
    float r2 = __fsub_rn(r1, __bfloat162float(m));     // exact
    __hip_bfloat16 l = __float2bfloat16(r2);
    hi[i] = h; mid[i] = m; lo[i] = l;
}

// ---------------- MFMA GEMM: C[M,N] = A[M,K](bf16,exact) * (Whi+Wmid+Wlo)[N,K]^T + bias ----------------
// m97-style: 128x128 tile, BK=32, 16x16x32 bf16 MFMA, global_load_lds width=16, 2-barrier K-loop.
// Products are exact (A in {0,1} or k/128); only fp32 accumulation-order error remains.
__global__ __launch_bounds__(256)
void snn_gemm_mfma(const __hip_bfloat16* __restrict__ A,
                   const __hip_bfloat16* __restrict__ Whi,
                   const __hip_bfloat16* __restrict__ Wmid,
                   const __hip_bfloat16* __restrict__ Wlo,
                   const float* __restrict__ bias,
                   float* __restrict__ C,
                   int M, int N, int K) {
    __shared__ __align__(16) unsigned short As[128 * 32];
    __shared__ __align__(16) unsigned short Bs[128 * 32];
    const int t    = threadIdx.x;
    const int wave = t >> 6;
    const int lane = t & 63;
    const int m0 = blockIdx.y * 128;
    const int n0 = blockIdx.x * 128;
    const int wm = (wave & 1) * 64;        // wave's 64x64 sub-tile
    const int wn = (wave >> 1) * 64;

    // staging coords: wave w stages rows [w*32, w*32+32); lane i covers row base+i/4, 16B chunk i%4
    const int srow = wave * 32 + (lane >> 2);
    const int scol = (lane & 3) * 8;       // bf16 elements

    // frag read coords (A-operand layout: dim = lane&15, k = (lane>>4)*8 + j)
    const int frow = lane & 15;
    const int fcol = (lane >> 4) * 8;

    f32x4 acc[4][4] = {};

    const __hip_bfloat16* parts[3] = {Whi, Wmid, Wlo};
    for (int part = 0; part < 3; ++part) {
        const __hip_bfloat16* Bw = parts[part];
        for (int k0 = 0; k0 < K; k0 += 32) {
            __syncthreads();   // WAR: previous tile's compute done before overwrite
            {
                const __hip_bfloat16* ga = A  + (size_t)(m0 + srow) * K + k0 + scol;
                const __hip_bfloat16* gb = Bw + (size_t)(n0 + srow) * K + k0 + scol;
                async16(ga,                    &As[srow * 32 + scol]);
                async16(ga + (size_t)16 * K,   &As[(srow + 16) * 32 + scol]);
                async16(gb,                    &Bs[srow * 32 + scol]);
                async16(gb + (size_t)16 * K,   &Bs[(srow + 16) * 32 + scol]);
            }
            __syncthreads();   // RAW: staging complete (compiler drains vmcnt before barrier)

            bf16x8 af[4], bfr[4];
            #pragma unroll
            for (int i = 0; i < 4; ++i) {
                af[i]  = *(const bf16x8*)&As[(wm + i * 16 + frow) * 32 + fcol];
                bfr[i] = *(const bf16x8*)&Bs[(wn + i * 16 + frow) * 32 + fcol];
            }
            #pragma unroll
            for (int i = 0; i < 4; ++i)
                #pragma unroll
                for (int j = 0; j < 4; ++j)
                    acc[i][j] = __builtin_amdgcn_mfma_f32_16x16x32_bf16(af[i], bfr[j], acc[i][j], 0, 0, 0);
        }
    }

    // epilogue: C/D layout col = lane&15, row = (lane>>4)*4 + reg  [m89/m91-verified]
    #pragma unroll
    for (int i = 0; i < 4; ++i) {
        int mg = m0 + wm + i * 16 + (lane >> 4) * 4;
        #pragma unroll
        for (int j = 0; j < 4; ++j) {
            int ng = n0 + wn + j * 16 + (lane & 15);
            float bb = bias[ng];
            #pragma unroll
            for (int r = 0; r < 4; ++r)
                C[(size_t)(mg + r) * N + ng] = acc[i][j][r] + bb;
        }
    }
}

// ---------------- LIF scan: 64 steps, fp32 ops bit-matching reference; bf16 spike out ----------------
__global__ void snn_lif_bf16(const float* __restrict__ cur, __hip_bfloat16* __restrict__ spk,
                             int BH, int bcast) {
    int idx = blockIdx.x * blockDim.x + threadIdx.x;
    if (idx >= BH) return;
    float mem = 0.0f;
    float cconst = bcast ? cur[idx] : 0.0f;
    for (int s = 0; s < S_STEPS; ++s) {
        float c = bcast ? cconst : cur[(size_t)s * BH + idx];
        float reset = (mem > 1.0f) ? 1.0f : 0.0f;
        float m1 = __fmul_rn(0.9f, mem);
        m1 = __fadd_rn(m1, c);
        m1 = __fsub_rn(m1, reset);
        mem = m1;
        spk[(size_t)s * BH + idx] = __float2bfloat16((mem > 1.0f) ? 1.0f : 0.0f); // 0/1 exact
    }
}

__global__ void snn_lif_f32(const float* __restrict__ cur, float* __restrict__ spk, int BH) {
    int idx = blockIdx.x * blockDim.x + threadIdx.x;
    if (idx >= BH) return;
    float mem = 0.0f;
    for (int s = 0; s < S_STEPS; ++s) {
        float c = cur[(size_t)s * BH + idx];
        float reset = (mem > 1.0f) ? 1.0f : 0.0f;
        float m1 = __fmul_rn(0.9f, mem);
        m1 = __fadd_rn(m1, c);
        m1 = __fsub_rn(m1, reset);
        mem = m1;
        spk[(size_t)s * BH + idx] = (mem > 1.0f) ? 1.0f : 0.0f;
    }
}

extern "C" void kernel_launch(void* const* d_in, const int* in_sizes, int n_in,
                              void* d_out, int out_size, void* d_ws, size_t ws_size,
                              hipStream_t stream) {
    const float* x  = (const float*)d_in[0];
    const float* W0 = (const float*)d_in[1];
    const float* b0 = (const float*)d_in[2];
    const float* W1 = (const float*)d_in[3];
    const float* b1 = (const float*)d_in[4];
    const float* W2 = (const float*)d_in[5];
    const float* b2 = (const float*)d_in[6];

    const int B = 256, T = 128, F = 512, H1 = 1024, H2 = 1024, H3 = 512;
    const int SB = S_STEPS * B;            // 16384

    // ---- workspace carve-up (bytes), all 16B aligned; total ~115 MB ----
    char* w = (char*)d_ws;
    __hip_bfloat16* spkA = (__hip_bfloat16*)w;              w += (size_t)SB * H1 * 2;   // 33.5 MB
    float*          curB = (float*)w;                       w += (size_t)SB * H1 * 4;   // 67 MB
    __hip_bfloat16* r_bf = (__hip_bfloat16*)w;              w += (size_t)B * F * 2;     // 256 KB
    float*          cur0 = (float*)w;                       w += (size_t)B * H1 * 4;    // 1 MB
    __hip_bfloat16* W0s  = (__hip_bfloat16*)w;              w += (size_t)3 * H1 * F * 2;
    __hip_bfloat16* W1s  = (__hip_bfloat16*)w;              w += (size_t)3 * H2 * H1 * 2;
    __hip_bfloat16* W2s  = (__hip_bfloat16*)w;              w += (size_t)3 * H3 * H2 * 2;

    const int nW0 = H1 * F, nW1 = H2 * H1, nW2 = H3 * H2;

    // weight splits (exact 3-term bf16 decomposition)
    split_w<<<dim3((nW0 + 255) / 256), dim3(256), 0, stream>>>(W0, W0s, W0s + nW0, W0s + 2 * nW0, nW0);
    split_w<<<dim3((nW1 + 255) / 256), dim3(256), 0, stream>>>(W1, W1s, W1s + nW1, W1s + 2 * nW1, nW1);
    split_w<<<dim3((nW2 + 255) / 256), dim3(256), 0, stream>>>(W2, W2s, W2s + nW2, W2s + 2 * nW2, nW2);

    // 1. delta encoder -> exact bf16 rates [B, F]
    snn_encoder<<<dim3((B * F + 255) / 256), dim3(256), 0, stream>>>(x, r_bf, B, T, F);

    // 2. cur0 = r @ W0^T + b0   [256 x 1024, K=512]
    snn_gemm_mfma<<<dim3(H1 / 128, B / 128), dim3(256), 0, stream>>>(
        r_bf, W0s, W0s + nW0, W0s + 2 * nW0, b0, cur0, B, H1, F);

    // 3. LIF layer 0 (broadcast current) -> spk0 bf16 [S, B*H1]
    snn_lif_bf16<<<dim3(B * H1 / 256), dim3(256), 0, stream>>>(cur0, spkA, B * H1, 1);

    // 4. cur1 = spk0 @ W1^T + b1   [16384 x 1024, K=1024]
    snn_gemm_mfma<<<dim3(H2 / 128, SB / 128), dim3(256), 0, stream>>>(
        spkA, W1s, W1s + nW1, W1s + 2 * nW1, b1, curB, SB, H2, H1);

    // 5. LIF layer 1 -> spk1 bf16 (reuse spkA)
    snn_lif_bf16<<<dim3(B * H2 / 256), dim3(256), 0, stream>>>(curB, spkA, B * H2, 0);

    // 6. cur2 = spk1 @ W2^T + b2   [16384 x 512, K=1024] (reuse curB)
    snn_gemm_mfma<<<dim3(H3 / 128, SB / 128), dim3(256), 0, stream>>>(
        spkA, W2s, W2s + nW2, W2s + 2 * nW2, b2, curB, SB, H3, H2);

    // 7. LIF layer 2 -> d_out fp32 [S, B*H3]
    snn_lif_f32<<<dim3(B * H3 / 256), dim3(256), 0, stream>>>(curB, (float*)d_out, B * H3);
}

// Round 5
// 463.026 us; speedup vs baseline: 1.8426x; 1.0448x over previous
//
#include <hip/hip_runtime.h>
#include <hip/hip_bf16.h>

#define S_STEPS 64

typedef __bf16 bf16x8 __attribute__((ext_vector_type(8)));
typedef float  f32x4  __attribute__((ext_vector_type(4)));

// ---- async 16B global->LDS (wave-uniform base + lane*16 contiguous dest) ----
__device__ __forceinline__ void async16(const void* g, void* l) {
    __builtin_amdgcn_global_load_lds((const __attribute__((address_space(1))) void*)g,
                                     (__attribute__((address_space(3))) void*)l,
                                     16, 0, 0);
}

// ---------------- encoder: r[b,f] = mean_t( (x[b,t,f]-x[b-1,t,f]) >= 0.2 ) ----------------
// count <= 128 is an integer -> k/128 is EXACT in bf16 (8 significant bits).
__global__ void snn_encoder(const float* __restrict__ x, __hip_bfloat16* __restrict__ r,
                            int B, int T, int F) {
    int idx = blockIdx.x * blockDim.x + threadIdx.x;   // b*F + f
    if (idx >= B * F) return;
    int b = idx / F;
    int f = idx - b * F;
    if (b == 0) { r[idx] = __float2bfloat16(0.0f); return; }
    const float* xb = x + (size_t)b * T * F + f;
    const float* xp = xb - (size_t)T * F;
    int cnt = 0;
    for (int t = 0; t < T; ++t) {
        float d = __fsub_rn(xb[(size_t)t * F], xp[(size_t)t * F]);
        cnt += (d >= 0.2f) ? 1 : 0;
    }
    r[idx] = __float2bfloat16((float)cnt * (1.0f / 128.0f));   // exact
}

// ---------------- 3-way bf16 split of fp32 weights: W == hi + mid + lo (to ~2^-25) ----------------
__global__ void split_w(const float* __restrict__ W,
                        __hip_bfloat16* __restrict__ hi,
                        __hip_bfloat16* __restrict__ mid,
                        __hip_bfloat16* __restrict__ lo, int n) {
    int i = blockIdx.x * blockDim.x + threadIdx.x;
    if (i >= n) return;
    float w = W[i];
    __hip_bfloat16 h = __float2bfloat16(w);
    float r1 = __fsub_rn(w, __bfloat162float(h));      // exact
    __hip_bfloat16 m = __float2bfloat16(r1);
    float r2 = __fsub_rn(r1, __bfloat162float(m));     // exact
    __hip_bfloat16 l = __float2bfloat16(r2);
    hi[i] = h; mid[i] = m; lo[i] = l;
}

// ---------------- MFMA GEMM: C[M,N] = A[M,K](bf16,exact) * (Whi+Wmid+Wlo)[N,K]^T + bias ----------------
// EXACT copy of the R2 kernel that passed (part-outer loop, 16KB LDS, 4 DMA/lane)
// with ONE change: bijective XCD-aware tile swizzle (bisect step).
__global__ __launch_bounds__(256)
void snn_gemm_mfma(const __hip_bfloat16* __restrict__ A,
                   const __hip_bfloat16* __restrict__ Whi,
                   const __hip_bfloat16* __restrict__ Wmid,
                   const __hip_bfloat16* __restrict__ Wlo,
                   const float* __restrict__ bias,
                   float* __restrict__ C,
                   int M, int N, int K) {
    __shared__ __align__(16) unsigned short As[128 * 32];
    __shared__ __align__(16) unsigned short Bs[128 * 32];
    const int t    = threadIdx.x;
    const int wave = t >> 6;
    const int lane = t & 63;

    // XCD-aware swizzle (bijective): flat%8 -> XCD owns contiguous M-band of tiles.
    int m_idx, n_idx;
    {
        int gx = gridDim.x, gy = gridDim.y;
        int flat = blockIdx.y * gx + blockIdx.x;
        if ((gy & 7) == 0) {
            int x = flat & 7, local = flat >> 3, h = gy >> 3;
            m_idx = x * h + (local % h);
            n_idx = local / h;
        } else { m_idx = blockIdx.y; n_idx = blockIdx.x; }
    }
    const int m0 = m_idx * 128;
    const int n0 = n_idx * 128;
    const int wm = (wave & 1) * 64;        // wave's 64x64 sub-tile
    const int wn = (wave >> 1) * 64;

    // staging coords: wave w stages rows [w*32, w*32+32); lane i covers row base+i/4, 16B chunk i%4
    const int srow = wave * 32 + (lane >> 2);
    const int scol = (lane & 3) * 8;       // bf16 elements

    // frag read coords (A-operand layout: dim = lane&15, k = (lane>>4)*8 + j)
    const int frow = lane & 15;
    const int fcol = (lane >> 4) * 8;

    f32x4 acc[4][4] = {};

    const __hip_bfloat16* parts[3] = {Whi, Wmid, Wlo};
    for (int part = 0; part < 3; ++part) {
        const __hip_bfloat16* Bw = parts[part];
        for (int k0 = 0; k0 < K; k0 += 32) {
            __syncthreads();   // WAR: previous tile's compute done before overwrite
            {
                const __hip_bfloat16* ga = A  + (size_t)(m0 + srow) * K + k0 + scol;
                const __hip_bfloat16* gb = Bw + (size_t)(n0 + srow) * K + k0 + scol;
                async16(ga,                    &As[srow * 32 + scol]);
                async16(ga + (size_t)16 * K,   &As[(srow + 16) * 32 + scol]);
                async16(gb,                    &Bs[srow * 32 + scol]);
                async16(gb + (size_t)16 * K,   &Bs[(srow + 16) * 32 + scol]);
            }
            __syncthreads();   // RAW: staging complete (compiler drains vmcnt before barrier)

            bf16x8 af[4], bfr[4];
            #pragma unroll
            for (int i = 0; i < 4; ++i) {
                af[i]  = *(const bf16x8*)&As[(wm + i * 16 + frow) * 32 + fcol];
                bfr[i] = *(const bf16x8*)&Bs[(wn + i * 16 + frow) * 32 + fcol];
            }
            #pragma unroll
            for (int i = 0; i < 4; ++i)
                #pragma unroll
                for (int j = 0; j < 4; ++j)
                    acc[i][j] = __builtin_amdgcn_mfma_f32_16x16x32_bf16(af[i], bfr[j], acc[i][j], 0, 0, 0);
        }
    }

    // epilogue: C/D layout col = lane&15, row = (lane>>4)*4 + reg  [m89/m91-verified]
    #pragma unroll
    for (int i = 0; i < 4; ++i) {
        int mg = m0 + wm + i * 16 + (lane >> 4) * 4;
        #pragma unroll
        for (int j = 0; j < 4; ++j) {
            int ng = n0 + wn + j * 16 + (lane & 15);
            float bb = bias[ng];
            #pragma unroll
            for (int r = 0; r < 4; ++r)
                C[(size_t)(mg + r) * N + ng] = acc[i][j][r] + bb;
        }
    }
}

// ---------------- LIF scan: 64 steps, fp32 ops bit-matching reference; bf16 spike out ----------------
__global__ void snn_lif_bf16(const float* __restrict__ cur, __hip_bfloat16* __restrict__ spk,
                             int BH, int bcast) {
    int idx = blockIdx.x * blockDim.x + threadIdx.x;
    if (idx >= BH) return;
    float mem = 0.0f;
    float cconst = bcast ? cur[idx] : 0.0f;
    for (int s = 0; s < S_STEPS; ++s) {
        float c = bcast ? cconst : cur[(size_t)s * BH + idx];
        float reset = (mem > 1.0f) ? 1.0f : 0.0f;
        float m1 = __fmul_rn(0.9f, mem);
        m1 = __fadd_rn(m1, c);
        m1 = __fsub_rn(m1, reset);
        mem = m1;
        spk[(size_t)s * BH + idx] = __float2bfloat16((mem > 1.0f) ? 1.0f : 0.0f); // 0/1 exact
    }
}

__global__ void snn_lif_f32(const float* __restrict__ cur, float* __restrict__ spk, int BH) {
    int idx = blockIdx.x * blockDim.x + threadIdx.x;
    if (idx >= BH) return;
    float mem = 0.0f;
    for (int s = 0; s < S_STEPS; ++s) {
        float c = cur[(size_t)s * BH + idx];
        float reset = (mem > 1.0f) ? 1.0f : 0.0f;
        float m1 = __fmul_rn(0.9f, mem);
        m1 = __fadd_rn(m1, c);
        m1 = __fsub_rn(m1, reset);
        mem = m1;
        spk[(size_t)s * BH + idx] = (mem > 1.0f) ? 1.0f : 0.0f;
    }
}

extern "C" void kernel_launch(void* const* d_in, const int* in_sizes, int n_in,
                              void* d_out, int out_size, void* d_ws, size_t ws_size,
                              hipStream_t stream) {
    const float* x  = (const float*)d_in[0];
    const float* W0 = (const float*)d_in[1];
    const float* b0 = (const float*)d_in[2];
    const float* W1 = (const float*)d_in[3];
    const float* b1 = (const float*)d_in[4];
    const float* W2 = (const float*)d_in[5];
    const float* b2 = (const float*)d_in[6];

    const int B = 256, T = 128, F = 512, H1 = 1024, H2 = 1024, H3 = 512;
    const int SB = S_STEPS * B;            // 16384

    // ---- workspace carve-up, all 16B aligned; total ~115 MB ----
    char* w = (char*)d_ws;
    __hip_bfloat16* spkA = (__hip_bfloat16*)w;              w += (size_t)SB * H1 * 2;   // 33.5 MB
    float*          curB = (float*)w;                       w += (size_t)SB * H1 * 4;   // 67 MB
    __hip_bfloat16* r_bf = (__hip_bfloat16*)w;              w += (size_t)B * F * 2;     // 256 KB
    float*          cur0 = (float*)w;                       w += (size_t)B * H1 * 4;    // 1 MB
    __hip_bfloat16* W0s  = (__hip_bfloat16*)w;              w += (size_t)3 * H1 * F * 2;
    __hip_bfloat16* W1s  = (__hip_bfloat16*)w;              w += (size_t)3 * H2 * H1 * 2;
    __hip_bfloat16* W2s  = (__hip_bfloat16*)w;              w += (size_t)3 * H3 * H2 * 2;

    const int nW0 = H1 * F, nW1 = H2 * H1, nW2 = H3 * H2;

    // weight splits (exact 3-term bf16 decomposition)
    split_w<<<dim3((nW0 + 255) / 256), dim3(256), 0, stream>>>(W0, W0s, W0s + nW0, W0s + 2 * nW0, nW0);
    split_w<<<dim3((nW1 + 255) / 256), dim3(256), 0, stream>>>(W1, W1s, W1s + nW1, W1s + 2 * nW1, nW1);
    split_w<<<dim3((nW2 + 255) / 256), dim3(256), 0, stream>>>(W2, W2s, W2s + nW2, W2s + 2 * nW2, nW2);

    // 1. delta encoder -> exact bf16 rates [B, F]
    snn_encoder<<<dim3((B * F + 255) / 256), dim3(256), 0, stream>>>(x, r_bf, B, T, F);

    // 2. cur0 = r @ W0^T + b0   [256 x 1024, K=512]
    snn_gemm_mfma<<<dim3(H1 / 128, B / 128), dim3(256), 0, stream>>>(
        r_bf, W0s, W0s + nW0, W0s + 2 * nW0, b0, cur0, B, H1, F);

    // 3. LIF layer 0 (broadcast current) -> spk0 bf16 [S, B*H1]
    snn_lif_bf16<<<dim3(B * H1 / 256), dim3(256), 0, stream>>>(cur0, spkA, B * H1, 1);

    // 4. cur1 = spk0 @ W1^T + b1   [16384 x 1024, K=1024]
    snn_gemm_mfma<<<dim3(H2 / 128, SB / 128), dim3(256), 0, stream>>>(
        spkA, W1s, W1s + nW1, W1s + 2 * nW1, b1, curB, SB, H2, H1);

    // 5. LIF layer 1 -> spk1 bf16 (reuse spkA)
    snn_lif_bf16<<<dim3(B * H2 / 256), dim3(256), 0, stream>>>(curB, spkA, B * H2, 0);

    // 6. cur2 = spk1 @ W2^T + b2   [16384 x 512, K=1024] (reuse curB)
    snn_gemm_mfma<<<dim3(H3 / 128, SB / 128), dim3(256), 0, stream>>>(
        spkA, W2s, W2s + nW2, W2s + 2 * nW2, b2, curB, SB, H3, H2);

    // 7. LIF layer 2 -> d_out fp32 [S, B*H3]
    snn_lif_f32<<<dim3(B * H3 / 256), dim3(256), 0, stream>>>(curB, (float*)d_out, B * H3);
}